// Round 1
// baseline (1969.882 us; speedup 1.0000x reference)
//
#include <hip/hip_runtime.h>

typedef __attribute__((ext_vector_type(8))) short s8v;
typedef __attribute__((ext_vector_type(8))) __bf16 bf8v;
typedef __attribute__((ext_vector_type(4))) float f32x4;

#define DEVINL __device__ __forceinline__

DEVINL unsigned short f2bf(float f) {
    unsigned int x = __float_as_uint(f);
    unsigned int r = (x + 0x7FFFu + ((x >> 16) & 1u)) >> 16;
    return (unsigned short)r;
}

DEVINL f32x4 mfma16(s8v a, s8v b, f32x4 c) {
    return __builtin_amdgcn_mfma_f32_16x16x32_bf16(
        __builtin_bit_cast(bf8v, a), __builtin_bit_cast(bf8v, b), c, 0, 0, 0);
}

// ---------------- workspace layout (bytes) ----------------
#define WS_FLAGS 0                       // [2 layers][2 dirs][16] flags, 64B apart = 4096
#define WS_HBUF  4096                    // [2][2][2 par][32][512] bf16 = 262144
#define WS_ZERO_BYTES 266240
#define WS_WIH   266240                  // bf16 [2][2][1536][1024] = 12582912
#define WS_WHH   (WS_WIH + 12582912)     // bf16 [2][2][1536][512]  = 6291456
#define WS_EMB   (WS_WHH + 6291456)      // bf16 [2048][1024] = 4194304
#define WS_ST1   (WS_EMB + 4194304)      // bf16 [2048][1024] = 4194304
#define WS_GX    (WS_ST1 + 4194304)      // f32  [2048][3072] = 25165824

// ---------------- fp32 -> bf16 convert ----------------
__global__ __launch_bounds__(256) void k_cvt(const float* __restrict__ in,
                                             unsigned short* __restrict__ out, int n) {
    int i0 = (blockIdx.x * 256 + threadIdx.x) * 8;
    if (i0 + 8 > n) return;
    f32x4 a = *(const f32x4*)(in + i0);
    f32x4 b = *(const f32x4*)(in + i0 + 4);
    s8v o;
    o[0] = (short)f2bf(a[0]); o[1] = (short)f2bf(a[1]);
    o[2] = (short)f2bf(a[2]); o[3] = (short)f2bf(a[3]);
    o[4] = (short)f2bf(b[0]); o[5] = (short)f2bf(b[1]);
    o[6] = (short)f2bf(b[2]); o[7] = (short)f2bf(b[3]);
    *(s8v*)(out + i0) = o;
}

// ---------------- conv softmax-attention ----------------
// one block per (b,s): scores[f][p] = conv_w[f].x[p] + conv_b; softmax over p;
// vec[f][i] = sum_p wts[f][p] x[p][i];  emits conv_wts (f32 out) + embedding (bf16)
__global__ __launch_bounds__(256) void k_conv(const float* __restrict__ inp,
                                              const float* __restrict__ conv_w,
                                              const float* __restrict__ conv_b,
                                              float* __restrict__ wts_out,
                                              unsigned short* __restrict__ emb) {
    const int bs = blockIdx.x, tid = threadIdx.x;
    __shared__ float xs[32][260];
    __shared__ float sc[4][32];
    __shared__ float wts[4][32];
    const float* x = inp + (size_t)bs * 8192;
    {
        int p = tid >> 3, i0 = (tid & 7) * 32;
        const float* src = x + p * 256 + i0;
        float* dst = &xs[p][i0];
#pragma unroll
        for (int j = 0; j < 32; j += 4) *(f32x4*)(dst + j) = *(const f32x4*)(src + j);
    }
    __syncthreads();
    {
        int p = tid >> 3, o = tid & 7;
        float s0 = 0, s1 = 0, s2 = 0, s3 = 0;
        const float* xp = &xs[p][o * 32];
#pragma unroll
        for (int j = 0; j < 32; j += 4) {
            f32x4 v  = *(const f32x4*)(xp + j);
            f32x4 w0 = *(const f32x4*)(conv_w + o * 32 + j);
            f32x4 w1 = *(const f32x4*)(conv_w + 256 + o * 32 + j);
            f32x4 w2 = *(const f32x4*)(conv_w + 512 + o * 32 + j);
            f32x4 w3 = *(const f32x4*)(conv_w + 768 + o * 32 + j);
#pragma unroll
            for (int q = 0; q < 4; ++q) {
                s0 += v[q] * w0[q]; s1 += v[q] * w1[q];
                s2 += v[q] * w2[q]; s3 += v[q] * w3[q];
            }
        }
#pragma unroll
        for (int d = 4; d; d >>= 1) {
            s0 += __shfl_down(s0, d, 8); s1 += __shfl_down(s1, d, 8);
            s2 += __shfl_down(s2, d, 8); s3 += __shfl_down(s3, d, 8);
        }
        if (o == 0) {
            sc[0][p] = s0 + conv_b[0]; sc[1][p] = s1 + conv_b[1];
            sc[2][p] = s2 + conv_b[2]; sc[3][p] = s3 + conv_b[3];
        }
    }
    __syncthreads();
    if (tid < 4) {
        float mx = -1e30f;
        for (int p = 0; p < 32; ++p) mx = fmaxf(mx, sc[tid][p]);
        float sm = 0.f;
        for (int p = 0; p < 32; ++p) { float e = __expf(sc[tid][p] - mx); wts[tid][p] = e; sm += e; }
        float inv = 1.f / sm;
        for (int p = 0; p < 32; ++p) wts[tid][p] *= inv;
    }
    __syncthreads();
    if (tid < 128) wts_out[(size_t)bs * 128 + tid] = wts[tid >> 5][tid & 31];
    {
        float a0 = 0, a1 = 0, a2 = 0, a3 = 0;
#pragma unroll 8
        for (int p = 0; p < 32; ++p) {
            float v = xs[p][tid];
            a0 += wts[0][p] * v; a1 += wts[1][p] * v;
            a2 += wts[2][p] * v; a3 += wts[3][p] * v;
        }
        unsigned short* e = emb + (size_t)bs * 1024;
        e[tid] = f2bf(a0); e[256 + tid] = f2bf(a1);
        e[512 + tid] = f2bf(a2); e[768 + tid] = f2bf(a3);
    }
}

// ---------------- bf16 GEMM: C[M][N] = A[M][K] * B[N][K]^T + bias[N] ----------------
__global__ __launch_bounds__(256, 2) void k_gemm(const unsigned short* __restrict__ A,
                                                 const unsigned short* __restrict__ B,
                                                 const float* __restrict__ bias,
                                                 float* __restrict__ C,
                                                 int M, int N, int K) {
    const int bm = blockIdx.y * 64, bn = blockIdx.x * 64;
    const int tid = threadIdx.x, w = tid >> 6, l = tid & 63;
    const int wm = (w >> 1) * 32, wn = (w & 1) * 32;
    __shared__ unsigned short As[64][72];
    __shared__ unsigned short Bs[64][72];
    f32x4 acc[2][2] = {};
    const int sr = tid >> 2;       // staging row 0..63
    const int sk = (tid & 3) * 8;  // staging k-offset
    const int am = (l & 15), ak = (l >> 4) * 8;
    for (int k0 = 0; k0 < K; k0 += 64) {
        s8v a0 = *(const s8v*)(A + (size_t)(bm + sr) * K + k0 + sk);
        s8v a1 = *(const s8v*)(A + (size_t)(bm + sr) * K + k0 + sk + 32);
        s8v b0 = *(const s8v*)(B + (size_t)(bn + sr) * K + k0 + sk);
        s8v b1 = *(const s8v*)(B + (size_t)(bn + sr) * K + k0 + sk + 32);
        __syncthreads();
        *(s8v*)&As[sr][sk] = a0; *(s8v*)&As[sr][sk + 32] = a1;
        *(s8v*)&Bs[sr][sk] = b0; *(s8v*)&Bs[sr][sk + 32] = b1;
        __syncthreads();
#pragma unroll
        for (int kk = 0; kk < 64; kk += 32) {
            s8v fa0 = *(const s8v*)&As[wm + am][kk + ak];
            s8v fa1 = *(const s8v*)&As[wm + 16 + am][kk + ak];
            s8v fb0 = *(const s8v*)&Bs[wn + am][kk + ak];
            s8v fb1 = *(const s8v*)&Bs[wn + 16 + am][kk + ak];
            acc[0][0] = mfma16(fa0, fb0, acc[0][0]);
            acc[0][1] = mfma16(fa0, fb1, acc[0][1]);
            acc[1][0] = mfma16(fa1, fb0, acc[1][0]);
            acc[1][1] = mfma16(fa1, fb1, acc[1][1]);
        }
    }
#pragma unroll
    for (int mt = 0; mt < 2; ++mt)
#pragma unroll
        for (int nt = 0; nt < 2; ++nt)
#pragma unroll
            for (int r = 0; r < 4; ++r) {
                int row = bm + wm + mt * 16 + (l >> 4) * 4 + r;
                int col = bn + wn + nt * 16 + (l & 15);
                C[(size_t)row * N + col] = acc[mt][nt][r] + bias[col];
            }
}

// ---------------- GRU scan (one layer, both directions) ----------------
// 32 blocks: dir = blk>>4, jg = blk&15 (owns h columns [jg*32, jg*32+32)).
// whh slice (96 cols x 512 K) lives in VGPRs as MFMA B-fragments.
// Per step: gh = h @ whh_slice^T via MFMA, gates in fp32, h' broadcast via
// double-buffered global bf16 buffer + per-block monotonic flags (device scope).
__global__ __launch_bounds__(384, 2) void k_scan(const float* __restrict__ gx,   // [2048][3072]
                                                 const unsigned short* __restrict__ whh, // [2][1536][512]
                                                 const float* __restrict__ bhh,  // [2][1536]
                                                 unsigned short* __restrict__ hbuf, // [2][2][32][512]
                                                 unsigned int* __restrict__ flags,  // [2][16*16]
                                                 float* __restrict__ st32,
                                                 unsigned short* __restrict__ st16) {
    const int blk = blockIdx.x;
    const int dir = blk >> 4, jg = blk & 15;
    const int tid = threadIdx.x;
    const int w = tid >> 6, l = tid & 63;
    __shared__ float gh[32][96];
    __shared__ float hprev[32][32];
    for (int i = tid; i < 1024; i += 384) ((float*)hprev)[i] = 0.f;

    // persistent B fragments: wave w covers gh columns cl = w*16 + (l&15)
    const int cl = w * 16 + (l & 15);
    const int R = (cl >> 5) * 512 + jg * 32 + (cl & 31);
    s8v bfrag[16];
    {
        const unsigned short* wr = whh + ((size_t)dir * 1536 + R) * 512 + (l >> 4) * 8;
#pragma unroll
        for (int kt = 0; kt < 16; ++kt) bfrag[kt] = *(const s8v*)(wr + kt * 32);
    }
    unsigned short* hb0 = hbuf + (size_t)dir * 2 * 16384;
    unsigned int* fl = flags + dir * 256;
    const float* bh = bhh + dir * 1536;
    const int jbase = jg * 32;

    for (int t = 0; t < 64; ++t) {
        const int s = dir ? (63 - t) : t;
        if (t > 0) {
            if (l < 16) {
                while (__hip_atomic_load(&fl[l * 16], __ATOMIC_ACQUIRE,
                                         __HIP_MEMORY_SCOPE_AGENT) < (unsigned)t) {
                    __builtin_amdgcn_s_sleep(1);
                }
            }
        }
        const unsigned short* hc = hb0 + (size_t)(t & 1) * 16384;
        {
            f32x4 acc0 = {0.f, 0.f, 0.f, 0.f}, acc1 = {0.f, 0.f, 0.f, 0.f};
            const unsigned short* ha = hc + (l & 15) * 512 + (l >> 4) * 8;
#pragma unroll
            for (int kt = 0; kt < 16; ++kt) {
                s8v a0 = *(const s8v*)(ha + kt * 32);
                s8v a1 = *(const s8v*)(ha + 16 * 512 + kt * 32);
                acc0 = mfma16(a0, bfrag[kt], acc0);
                acc1 = mfma16(a1, bfrag[kt], acc1);
            }
#pragma unroll
            for (int r = 0; r < 4; ++r) {
                gh[(l >> 4) * 4 + r][cl] = acc0[r];
                gh[16 + (l >> 4) * 4 + r][cl] = acc1[r];
            }
        }
        __syncthreads();
        unsigned short* hn_out = hb0 + (size_t)((t + 1) & 1) * 16384;
        for (int idx = tid; idx < 1024; idx += 384) {
            const int b = idx >> 5, jj = idx & 31;
            const int j = jbase + jj;
            const float* gxp = gx + (size_t)(b * 64 + s) * 3072 + dir * 1536;
            float xr = gxp[j], xz = gxp[512 + j], xn = gxp[1024 + j];
            float hr = gh[b][jj] + bh[j];
            float hz = gh[b][32 + jj] + bh[512 + j];
            float hnv = gh[b][64 + jj] + bh[1024 + j];
            float r_ = 1.f / (1.f + __expf(-(xr + hr)));
            float z_ = 1.f / (1.f + __expf(-(xz + hz)));
            float n_ = tanhf(xn + r_ * hnv);
            float hp = hprev[b][jj];
            float hv = (1.f - z_) * n_ + z_ * hp;
            hprev[b][jj] = hv;
            hn_out[b * 512 + j] = f2bf(hv);
            const size_t so = (size_t)(b * 64 + s) * 1024 + dir * 512 + j;
            if (st32) st32[so] = hv;
            if (st16) st16[so] = f2bf(hv);
        }
        __threadfence();
        __syncthreads();
        if (tid == 0)
            __hip_atomic_store(&fl[jg * 16], (unsigned)(t + 1), __ATOMIC_RELEASE,
                               __HIP_MEMORY_SCOPE_AGENT);
    }
}

// ---------------- finale: alpha softmax over S, context, linear+softmax ----------------
__global__ __launch_bounds__(256) void k_finale(const float* __restrict__ states, // [32][64][1024]
                                                const float* __restrict__ conv2_w,
                                                const float* __restrict__ conv2_b,
                                                const float* __restrict__ demoip, // [32][3]
                                                const float* __restrict__ lin_w,  // [2][1027]
                                                const float* __restrict__ lin_b,  // [2]
                                                float* __restrict__ out,
                                                float* __restrict__ context,
                                                float* __restrict__ alpha) {
    const int b = blockIdx.x, tid = threadIdx.x, w = tid >> 6, l = tid & 63;
    __shared__ float dots[64], al[64], ctx[1024], lg[2];
    const float* st = states + (size_t)b * 65536;
    for (int si = 0; si < 16; ++si) {
        int s = w * 16 + si;
        const float* row = st + s * 1024;
        float sum = 0.f;
        for (int i = l; i < 1024; i += 64) sum += row[i] * conv2_w[i];
#pragma unroll
        for (int m = 32; m; m >>= 1) sum += __shfl_xor(sum, m, 64);
        if (l == 0) dots[s] = sum + conv2_b[0];
    }
    __syncthreads();
    if (w == 0) {
        float v = dots[l];
        float mx = v;
#pragma unroll
        for (int m = 32; m; m >>= 1) mx = fmaxf(mx, __shfl_xor(mx, m, 64));
        float e = __expf(v - mx);
        float sm = e;
#pragma unroll
        for (int m = 32; m; m >>= 1) sm += __shfl_xor(sm, m, 64);
        float a = e / sm;
        al[l] = a;
        alpha[b * 64 + l] = a;
    }
    __syncthreads();
    for (int h = tid; h < 1024; h += 256) {
        float c = 0.f;
#pragma unroll 8
        for (int s = 0; s < 64; ++s) c += al[s] * st[s * 1024 + h];
        ctx[h] = c;
        context[b * 1024 + h] = c;
    }
    __syncthreads();
    if (w < 2) {
        const float* lw = lin_w + w * 1027;
        float sum = 0.f;
        for (int i = l; i < 1024; i += 64) sum += ctx[i] * lw[i];
#pragma unroll
        for (int m = 32; m; m >>= 1) sum += __shfl_xor(sum, m, 64);
        if (l == 0) {
            sum += lw[1024] * demoip[b * 3] + lw[1025] * demoip[b * 3 + 1] +
                   lw[1026] * demoip[b * 3 + 2] + lin_b[w];
            lg[w] = sum;
        }
    }
    __syncthreads();
    if (tid == 0) {
        float m = fmaxf(lg[0], lg[1]);
        float e0 = __expf(lg[0] - m), e1 = __expf(lg[1] - m);
        float inv = 1.f / (e0 + e1);
        out[b * 2 + 0] = e0 * inv;
        out[b * 2 + 1] = e1 * inv;
    }
}

extern "C" void kernel_launch(void* const* d_in, const int* in_sizes, int n_in,
                              void* d_out, int out_size, void* d_ws, size_t ws_size,
                              hipStream_t stream) {
    const float* inputs  = (const float*)d_in[0];
    const float* demoip  = (const float*)d_in[1];
    const float* conv_w  = (const float*)d_in[2];
    const float* conv_b  = (const float*)d_in[3];
    const float* conv2_w = (const float*)d_in[4];
    const float* conv2_b = (const float*)d_in[5];
    const float* wih     = (const float*)d_in[6];
    const float* whh     = (const float*)d_in[7];
    const float* bih     = (const float*)d_in[8];
    const float* bhh     = (const float*)d_in[9];
    const float* lin_w   = (const float*)d_in[10];
    const float* lin_b   = (const float*)d_in[11];

    char* ws = (char*)d_ws;
    unsigned int* flags   = (unsigned int*)(ws + WS_FLAGS);
    unsigned short* hbuf  = (unsigned short*)(ws + WS_HBUF);
    unsigned short* wih16 = (unsigned short*)(ws + WS_WIH);
    unsigned short* whh16 = (unsigned short*)(ws + WS_WHH);
    unsigned short* emb16 = (unsigned short*)(ws + WS_EMB);
    unsigned short* st116 = (unsigned short*)(ws + WS_ST1);
    float* gxbuf          = (float*)(ws + WS_GX);

    float* out_out    = (float*)d_out;
    float* wts_out    = out_out + 64;
    float* states_out = out_out + 262208;
    float* ctx_out    = out_out + 2359360;
    float* alpha_out  = out_out + 2392128;

    hipMemsetAsync(ws, 0, WS_ZERO_BYTES, stream);
    k_cvt<<<3072, 256, 0, stream>>>(wih, wih16, 6291456);
    k_cvt<<<1536, 256, 0, stream>>>(whh, whh16, 3145728);
    k_conv<<<2048, 256, 0, stream>>>(inputs, conv_w, conv_b, wts_out, emb16);
    // layer 1
    k_gemm<<<dim3(48, 32), 256, 0, stream>>>(emb16, wih16, bih, gxbuf, 2048, 3072, 1024);
    k_scan<<<32, 384, 0, stream>>>(gxbuf, whh16, bhh, hbuf, flags, nullptr, st116);
    // layer 2
    k_gemm<<<dim3(48, 32), 256, 0, stream>>>(st116, wih16 + 3145728, bih + 3072, gxbuf,
                                             2048, 3072, 1024);
    k_scan<<<32, 384, 0, stream>>>(gxbuf, whh16 + 1572864, bhh + 3072, hbuf + 65536,
                                   flags + 512, states_out, nullptr);
    k_finale<<<32, 256, 0, stream>>>(states_out, conv2_w, conv2_b, demoip, lin_w, lin_b,
                                     out_out, ctx_out, alpha_out);
}

// Round 2
// 1075.234 us; speedup vs baseline: 1.8320x; 1.8320x over previous
//
#include <hip/hip_runtime.h>

typedef __attribute__((ext_vector_type(8))) short s8v;
typedef __attribute__((ext_vector_type(8))) __bf16 bf8v;
typedef __attribute__((ext_vector_type(4))) float f32x4;

#define DEVINL __device__ __forceinline__

DEVINL unsigned short f2bf(float f) {
    unsigned int x = __float_as_uint(f);
    unsigned int r = (x + 0x7FFFu + ((x >> 16) & 1u)) >> 16;
    return (unsigned short)r;
}

DEVINL f32x4 mfma16(s8v a, s8v b, f32x4 c) {
    return __builtin_amdgcn_mfma_f32_16x16x32_bf16(
        __builtin_bit_cast(bf8v, a), __builtin_bit_cast(bf8v, b), c, 0, 0, 0);
}

// ---------------- workspace layout (bytes) ----------------
#define WS_CTR   0                        // [2 layers][2 dirs] counters, 256B apart = 1024
#define WS_HBUF  1024                     // [2 layers][2 dirs][2 buf][32][512] bf16 = 262144
#define WS_ZERO_BYTES 263168
#define WS_WIH   263168                   // bf16 [2][2][1536][1024] = 12582912
#define WS_WHH   (WS_WIH + 12582912)      // bf16 [2][2][1536][512]  = 6291456
#define WS_EMB   (WS_WHH + 6291456)       // bf16 [2048][1024] = 4194304
#define WS_ST1   (WS_EMB + 4194304)       // bf16 [2048][1024] = 4194304
#define WS_GX    (WS_ST1 + 4194304)       // f32  [2048][3072] = 25165824

// ---------------- fp32 -> bf16 convert ----------------
__global__ __launch_bounds__(256) void k_cvt(const float* __restrict__ in,
                                             unsigned short* __restrict__ out, int n) {
    int i0 = (blockIdx.x * 256 + threadIdx.x) * 8;
    if (i0 + 8 > n) return;
    f32x4 a = *(const f32x4*)(in + i0);
    f32x4 b = *(const f32x4*)(in + i0 + 4);
    s8v o;
    o[0] = (short)f2bf(a[0]); o[1] = (short)f2bf(a[1]);
    o[2] = (short)f2bf(a[2]); o[3] = (short)f2bf(a[3]);
    o[4] = (short)f2bf(b[0]); o[5] = (short)f2bf(b[1]);
    o[6] = (short)f2bf(b[2]); o[7] = (short)f2bf(b[3]);
    *(s8v*)(out + i0) = o;
}

// ---------------- conv softmax-attention ----------------
__global__ __launch_bounds__(256) void k_conv(const float* __restrict__ inp,
                                              const float* __restrict__ conv_w,
                                              const float* __restrict__ conv_b,
                                              float* __restrict__ wts_out,
                                              unsigned short* __restrict__ emb) {
    const int bs = blockIdx.x, tid = threadIdx.x;
    __shared__ float xs[32][260];
    __shared__ float sc[4][32];
    __shared__ float wts[4][32];
    const float* x = inp + (size_t)bs * 8192;
    {
        int p = tid >> 3, i0 = (tid & 7) * 32;
        const float* src = x + p * 256 + i0;
        float* dst = &xs[p][i0];
#pragma unroll
        for (int j = 0; j < 32; j += 4) *(f32x4*)(dst + j) = *(const f32x4*)(src + j);
    }
    __syncthreads();
    {
        int p = tid >> 3, o = tid & 7;
        float s0 = 0, s1 = 0, s2 = 0, s3 = 0;
        const float* xp = &xs[p][o * 32];
#pragma unroll
        for (int j = 0; j < 32; j += 4) {
            f32x4 v  = *(const f32x4*)(xp + j);
            f32x4 w0 = *(const f32x4*)(conv_w + o * 32 + j);
            f32x4 w1 = *(const f32x4*)(conv_w + 256 + o * 32 + j);
            f32x4 w2 = *(const f32x4*)(conv_w + 512 + o * 32 + j);
            f32x4 w3 = *(const f32x4*)(conv_w + 768 + o * 32 + j);
#pragma unroll
            for (int q = 0; q < 4; ++q) {
                s0 += v[q] * w0[q]; s1 += v[q] * w1[q];
                s2 += v[q] * w2[q]; s3 += v[q] * w3[q];
            }
        }
#pragma unroll
        for (int d = 4; d; d >>= 1) {
            s0 += __shfl_down(s0, d, 8); s1 += __shfl_down(s1, d, 8);
            s2 += __shfl_down(s2, d, 8); s3 += __shfl_down(s3, d, 8);
        }
        if (o == 0) {
            sc[0][p] = s0 + conv_b[0]; sc[1][p] = s1 + conv_b[1];
            sc[2][p] = s2 + conv_b[2]; sc[3][p] = s3 + conv_b[3];
        }
    }
    __syncthreads();
    if (tid < 4) {
        float mx = -1e30f;
        for (int p = 0; p < 32; ++p) mx = fmaxf(mx, sc[tid][p]);
        float sm = 0.f;
        for (int p = 0; p < 32; ++p) { float e = __expf(sc[tid][p] - mx); wts[tid][p] = e; sm += e; }
        float inv = 1.f / sm;
        for (int p = 0; p < 32; ++p) wts[tid][p] *= inv;
    }
    __syncthreads();
    if (tid < 128) wts_out[(size_t)bs * 128 + tid] = wts[tid >> 5][tid & 31];
    {
        float a0 = 0, a1 = 0, a2 = 0, a3 = 0;
#pragma unroll 8
        for (int p = 0; p < 32; ++p) {
            float v = xs[p][tid];
            a0 += wts[0][p] * v; a1 += wts[1][p] * v;
            a2 += wts[2][p] * v; a3 += wts[3][p] * v;
        }
        unsigned short* e = emb + (size_t)bs * 1024;
        e[tid] = f2bf(a0); e[256 + tid] = f2bf(a1);
        e[512 + tid] = f2bf(a2); e[768 + tid] = f2bf(a3);
    }
}

// ---------------- bf16 GEMM: C[M][N] = A[M][K] * B[N][K]^T + bias[N] ----------------
__global__ __launch_bounds__(256, 2) void k_gemm(const unsigned short* __restrict__ A,
                                                 const unsigned short* __restrict__ B,
                                                 const float* __restrict__ bias,
                                                 float* __restrict__ C,
                                                 int M, int N, int K) {
    const int bm = blockIdx.y * 64, bn = blockIdx.x * 64;
    const int tid = threadIdx.x, w = tid >> 6, l = tid & 63;
    const int wm = (w >> 1) * 32, wn = (w & 1) * 32;
    __shared__ unsigned short As[64][72];
    __shared__ unsigned short Bs[64][72];
    f32x4 acc[2][2] = {};
    const int sr = tid >> 2;
    const int sk = (tid & 3) * 8;
    const int am = (l & 15), ak = (l >> 4) * 8;
    for (int k0 = 0; k0 < K; k0 += 64) {
        s8v a0 = *(const s8v*)(A + (size_t)(bm + sr) * K + k0 + sk);
        s8v a1 = *(const s8v*)(A + (size_t)(bm + sr) * K + k0 + sk + 32);
        s8v b0 = *(const s8v*)(B + (size_t)(bn + sr) * K + k0 + sk);
        s8v b1 = *(const s8v*)(B + (size_t)(bn + sr) * K + k0 + sk + 32);
        __syncthreads();
        *(s8v*)&As[sr][sk] = a0; *(s8v*)&As[sr][sk + 32] = a1;
        *(s8v*)&Bs[sr][sk] = b0; *(s8v*)&Bs[sr][sk + 32] = b1;
        __syncthreads();
#pragma unroll
        for (int kk = 0; kk < 64; kk += 32) {
            s8v fa0 = *(const s8v*)&As[wm + am][kk + ak];
            s8v fa1 = *(const s8v*)&As[wm + 16 + am][kk + ak];
            s8v fb0 = *(const s8v*)&Bs[wn + am][kk + ak];
            s8v fb1 = *(const s8v*)&Bs[wn + 16 + am][kk + ak];
            acc[0][0] = mfma16(fa0, fb0, acc[0][0]);
            acc[0][1] = mfma16(fa0, fb1, acc[0][1]);
            acc[1][0] = mfma16(fa1, fb0, acc[1][0]);
            acc[1][1] = mfma16(fa1, fb1, acc[1][1]);
        }
    }
#pragma unroll
    for (int mt = 0; mt < 2; ++mt)
#pragma unroll
        for (int nt = 0; nt < 2; ++nt)
#pragma unroll
            for (int r = 0; r < 4; ++r) {
                int row = bm + wm + mt * 16 + (l >> 4) * 4 + r;
                int col = bn + wn + nt * 16 + (l & 15);
                C[(size_t)row * N + col] = acc[mt][nt][r] + bias[col];
            }
}

// ---------------- GRU scan (one layer, both directions) ----------------
// 16 blocks: dir = blk>>3, jg = blk&7 owns h columns [jg*64, jg*64+64).
// 768 threads = 12 waves; wave w owns gh columns w*16..w*16+15 (192 total = 3 gates x 64).
// whh slice lives in VGPRs. Per step: prefetch gx -> relaxed-poll arrival counter ->
// stage h into LDS (XOR-swizzled) -> MFMA -> gates -> write-through h stores ->
// __syncthreads (vmcnt drain) -> one release atomicAdd.
__global__ __launch_bounds__(768, 1) void k_scan(const float* __restrict__ gx,   // [2048][3072]
                                                 const unsigned short* __restrict__ whh, // [2][1536][512]
                                                 const float* __restrict__ bhh,  // [2][1536]
                                                 unsigned short* __restrict__ hbuf, // [2 dir][2 buf][32][512]
                                                 unsigned int* __restrict__ ctrs,  // [2 dir] 64-uint stride
                                                 float* __restrict__ st32,
                                                 unsigned short* __restrict__ st16) {
    const int blk = blockIdx.x;
    const int dir = blk >> 3, jg = blk & 7;
    const int tid = threadIdx.x;
    const int w = tid >> 6, l = tid & 63;

    __shared__ __align__(1024) unsigned short hs[16384]; // [32][512] swizzled
    __shared__ float gh[32][196];
    __shared__ float hprev[32][64];
    for (int i = tid; i < 2048; i += 768) ((float*)hprev)[i] = 0.f;

    // persistent B fragments: wave w covers gh columns cl = w*16 + (l&15)
    const int cl = w * 16 + (l & 15);
    const int R = (cl >> 6) * 512 + jg * 64 + (cl & 63);
    s8v bfrag[16];
    {
        const unsigned short* wr = whh + ((size_t)dir * 1536 + R) * 512 + (l >> 4) * 8;
#pragma unroll
        for (int kt = 0; kt < 16; ++kt) bfrag[kt] = *(const s8v*)(wr + kt * 32);
    }
    unsigned short* hb0 = hbuf + (size_t)dir * 32768;
    unsigned int* ctr = ctrs + dir * 64;
    const float* bh = bhh + dir * 1536;
    const int jb = jg * 64;

    // gate-phase task split: 1024 tasks (b,jp), task0 = tid, task1 = 768+tid (tid<256)
    const int has2 = (tid < 256);

    for (int t = 0; t < 64; ++t) {
        const int s = dir ? (63 - t) : t;
        // ---- prefetch this step's gx (independent of h) ----
        float2 pr[2], pz[2], pn[2];
        {
            const int b0 = tid >> 5, jp0 = tid & 31;
            const float* g0 = gx + (size_t)(b0 * 64 + s) * 3072 + dir * 1536 + jb + jp0 * 2;
            pr[0] = *(const float2*)(g0);
            pz[0] = *(const float2*)(g0 + 512);
            pn[0] = *(const float2*)(g0 + 1024);
            if (has2) {
                const int tk1 = 768 + tid, b1 = tk1 >> 5, jp1 = tk1 & 31;
                const float* g1 = gx + (size_t)(b1 * 64 + s) * 3072 + dir * 1536 + jb + jp1 * 2;
                pr[1] = *(const float2*)(g1);
                pz[1] = *(const float2*)(g1 + 512);
                pn[1] = *(const float2*)(g1 + 1024);
            }
        }
        // ---- wait for all blocks of this direction to publish h_t ----
        if (t > 0 && l == 0) {
            while (__hip_atomic_load(ctr, __ATOMIC_RELAXED, __HIP_MEMORY_SCOPE_AGENT) <
                   (unsigned)(8 * t)) {
                __builtin_amdgcn_s_sleep(1);
            }
            (void)__hip_atomic_load(ctr, __ATOMIC_ACQUIRE, __HIP_MEMORY_SCOPE_AGENT);
        }
        __syncthreads();
        // ---- stage h_t into LDS (swizzled) ----
        const unsigned short* hc = hb0 + (size_t)(t & 1) * 16384;
        for (int c = tid; c < 2048; c += 768) {
            const int row = c >> 6, inb = (c & 63) * 16;
            *(s8v*)((char*)hs + row * 1024 + (inb ^ ((row & 7) << 4))) =
                *(const s8v*)(hc + c * 8);
        }
        __syncthreads();
        // ---- gh = h @ whh_slice^T via MFMA ----
        {
            f32x4 acc0 = {0.f, 0.f, 0.f, 0.f}, acc1 = {0.f, 0.f, 0.f, 0.f};
            const int q16 = (l >> 4) * 16;
            const int row0 = (l & 15), row1 = 16 + (l & 15);
            const int m = (row0 & 7) << 4;
#pragma unroll
            for (int kt = 0; kt < 16; ++kt) {
                const int inr = kt * 64 + q16;
                s8v a0 = *(const s8v*)((const char*)hs + row0 * 1024 + (inr ^ m));
                s8v a1 = *(const s8v*)((const char*)hs + row1 * 1024 + (inr ^ m));
                acc0 = mfma16(a0, bfrag[kt], acc0);
                acc1 = mfma16(a1, bfrag[kt], acc1);
            }
#pragma unroll
            for (int r = 0; r < 4; ++r) {
                gh[(l >> 4) * 4 + r][cl] = acc0[r];
                gh[16 + (l >> 4) * 4 + r][cl] = acc1[r];
            }
        }
        __syncthreads();
        // ---- gates + publish h_{t+1} ----
        unsigned int* hnw = (unsigned int*)(hb0 + (size_t)((t + 1) & 1) * 16384);
#pragma unroll
        for (int nt = 0; nt < 2; ++nt) {
            if (nt == 1 && !has2) break;
            const int task = nt ? 768 + tid : tid;
            const int b = task >> 5, jp = task & 31, jj = jp * 2, j = jb + jj;
            float hr0 = gh[b][jj]       + bh[j];
            float hr1 = gh[b][jj + 1]   + bh[j + 1];
            float hz0 = gh[b][64 + jj]  + bh[512 + j];
            float hz1 = gh[b][64 + jj + 1] + bh[512 + j + 1];
            float hn0 = gh[b][128 + jj] + bh[1024 + j];
            float hn1 = gh[b][128 + jj + 1] + bh[1024 + j + 1];
            float r0 = 1.f / (1.f + __expf(-(pr[nt].x + hr0)));
            float r1 = 1.f / (1.f + __expf(-(pr[nt].y + hr1)));
            float z0 = 1.f / (1.f + __expf(-(pz[nt].x + hz0)));
            float z1 = 1.f / (1.f + __expf(-(pz[nt].y + hz1)));
            float n0 = tanhf(pn[nt].x + r0 * hn0);
            float n1 = tanhf(pn[nt].y + r1 * hn1);
            float hp0 = hprev[b][jj], hp1 = hprev[b][jj + 1];
            float h0 = (1.f - z0) * n0 + z0 * hp0;
            float h1 = (1.f - z1) * n1 + z1 * hp1;
            hprev[b][jj] = h0; hprev[b][jj + 1] = h1;
            unsigned int packed = (unsigned int)f2bf(h0) | ((unsigned int)f2bf(h1) << 16);
            // write-through (agent-scope) store so vmcnt-drain == global visibility
            __hip_atomic_store(&hnw[b * 256 + (j >> 1)], packed, __ATOMIC_RELAXED,
                               __HIP_MEMORY_SCOPE_AGENT);
            const size_t so = (size_t)(b * 64 + s) * 1024 + dir * 512 + j;
            if (st32) *(float2*)(st32 + so) = make_float2(h0, h1);
            if (st16) *(unsigned int*)(st16 + so) = packed;
        }
        __syncthreads();  // drains vmcnt for all waves -> h stores globally visible
        if (tid == 0 && t < 63)
            (void)__hip_atomic_fetch_add(ctr, 1u, __ATOMIC_RELEASE, __HIP_MEMORY_SCOPE_AGENT);
    }
}

// ---------------- finale ----------------
__global__ __launch_bounds__(256) void k_finale(const float* __restrict__ states,
                                                const float* __restrict__ conv2_w,
                                                const float* __restrict__ conv2_b,
                                                const float* __restrict__ demoip,
                                                const float* __restrict__ lin_w,
                                                const float* __restrict__ lin_b,
                                                float* __restrict__ out,
                                                float* __restrict__ context,
                                                float* __restrict__ alpha) {
    const int b = blockIdx.x, tid = threadIdx.x, w = tid >> 6, l = tid & 63;
    __shared__ float dots[64], al[64], ctx[1024], lg[2];
    const float* st = states + (size_t)b * 65536;
    for (int si = 0; si < 16; ++si) {
        int s = w * 16 + si;
        const float* row = st + s * 1024;
        float sum = 0.f;
        for (int i = l; i < 1024; i += 64) sum += row[i] * conv2_w[i];
#pragma unroll
        for (int m = 32; m; m >>= 1) sum += __shfl_xor(sum, m, 64);
        if (l == 0) dots[s] = sum + conv2_b[0];
    }
    __syncthreads();
    if (w == 0) {
        float v = dots[l];
        float mx = v;
#pragma unroll
        for (int m = 32; m; m >>= 1) mx = fmaxf(mx, __shfl_xor(mx, m, 64));
        float e = __expf(v - mx);
        float sm = e;
#pragma unroll
        for (int m = 32; m; m >>= 1) sm += __shfl_xor(sm, m, 64);
        float a = e / sm;
        al[l] = a;
        alpha[b * 64 + l] = a;
    }
    __syncthreads();
    for (int h = tid; h < 1024; h += 256) {
        float c = 0.f;
#pragma unroll 8
        for (int s = 0; s < 64; ++s) c += al[s] * st[s * 1024 + h];
        ctx[h] = c;
        context[b * 1024 + h] = c;
    }
    __syncthreads();
    if (w < 2) {
        const float* lw = lin_w + w * 1027;
        float sum = 0.f;
        for (int i = l; i < 1024; i += 64) sum += ctx[i] * lw[i];
#pragma unroll
        for (int m = 32; m; m >>= 1) sum += __shfl_xor(sum, m, 64);
        if (l == 0) {
            sum += lw[1024] * demoip[b * 3] + lw[1025] * demoip[b * 3 + 1] +
                   lw[1026] * demoip[b * 3 + 2] + lin_b[w];
            lg[w] = sum;
        }
    }
    __syncthreads();
    if (tid == 0) {
        float m = fmaxf(lg[0], lg[1]);
        float e0 = __expf(lg[0] - m), e1 = __expf(lg[1] - m);
        float inv = 1.f / (e0 + e1);
        out[b * 2 + 0] = e0 * inv;
        out[b * 2 + 1] = e1 * inv;
    }
}

extern "C" void kernel_launch(void* const* d_in, const int* in_sizes, int n_in,
                              void* d_out, int out_size, void* d_ws, size_t ws_size,
                              hipStream_t stream) {
    const float* inputs  = (const float*)d_in[0];
    const float* demoip  = (const float*)d_in[1];
    const float* conv_w  = (const float*)d_in[2];
    const float* conv_b  = (const float*)d_in[3];
    const float* conv2_w = (const float*)d_in[4];
    const float* conv2_b = (const float*)d_in[5];
    const float* wih     = (const float*)d_in[6];
    const float* whh     = (const float*)d_in[7];
    const float* bih     = (const float*)d_in[8];
    const float* bhh     = (const float*)d_in[9];
    const float* lin_w   = (const float*)d_in[10];
    const float* lin_b   = (const float*)d_in[11];

    char* ws = (char*)d_ws;
    unsigned int* ctrs    = (unsigned int*)(ws + WS_CTR);
    unsigned short* hbuf  = (unsigned short*)(ws + WS_HBUF);
    unsigned short* wih16 = (unsigned short*)(ws + WS_WIH);
    unsigned short* whh16 = (unsigned short*)(ws + WS_WHH);
    unsigned short* emb16 = (unsigned short*)(ws + WS_EMB);
    unsigned short* st116 = (unsigned short*)(ws + WS_ST1);
    float* gxbuf          = (float*)(ws + WS_GX);

    float* out_out    = (float*)d_out;
    float* wts_out    = out_out + 64;
    float* states_out = out_out + 262208;
    float* ctx_out    = out_out + 2359360;
    float* alpha_out  = out_out + 2392128;

    hipMemsetAsync(ws, 0, WS_ZERO_BYTES, stream);
    k_cvt<<<3072, 256, 0, stream>>>(wih, wih16, 6291456);
    k_cvt<<<1536, 256, 0, stream>>>(whh, whh16, 3145728);
    k_conv<<<2048, 256, 0, stream>>>(inputs, conv_w, conv_b, wts_out, emb16);
    // layer 1
    k_gemm<<<dim3(48, 32), 256, 0, stream>>>(emb16, wih16, bih, gxbuf, 2048, 3072, 1024);
    k_scan<<<16, 768, 0, stream>>>(gxbuf, whh16, bhh, hbuf, ctrs, nullptr, st116);
    // layer 2
    k_gemm<<<dim3(48, 32), 256, 0, stream>>>(st116, wih16 + 3145728, bih + 3072, gxbuf,
                                             2048, 3072, 1024);
    k_scan<<<16, 768, 0, stream>>>(gxbuf, whh16 + 1572864, bhh + 3072, hbuf + 65536,
                                   ctrs + 128, states_out, nullptr);
    k_finale<<<32, 256, 0, stream>>>(states_out, conv2_w, conv2_b, demoip, lin_w, lin_b,
                                     out_out, ctx_out, alpha_out);
}